// Round 4
// baseline (381.488 us; speedup 1.0000x reference)
//
#include <hip/hip_runtime.h>

#define C      21
#define HW4    65536      // float4 groups per 512x512 plane
#define NGRP   1048576    // 16*512*512/4
#define NBLK   2048
#define GPT    2          // groups per thread: NBLK*256*GPT == NGRP
#define TICKET 63         // ws slot for the done-counter (hist uses 0..62)

typedef float f4 __attribute__((ext_vector_type(4)));
typedef int   i4 __attribute__((ext_vector_type(4)));

__global__ __launch_bounds__(256) void iou_kernel(
    const f4* __restrict__ pred, const i4* __restrict__ tgt,
    unsigned int* __restrict__ hist, float* __restrict__ out) {
  __shared__ unsigned int sh[3 * C];
  __shared__ int sh_last;
  const int tid  = threadIdx.x;
  if (tid < 3 * C) sh[tid] = 0;
  __syncthreads();
  const int lane = tid & 63;

  int idx[GPT][4];
  i4  tg[GPT];

#pragma unroll
  for (int q = 0; q < GPT; ++q) {
    const int g    = blockIdx.x * 256 + tid + q * (NBLK * 256);
    const int b    = g >> 16;
    const int hw4  = g & (HW4 - 1);
    const int base = ((b * C) << 16) + hw4;   // f4 index of channel 0, this pixel-group

    f4 best = pred[base];
    int i0 = 0, i1 = 0, i2 = 0, i3 = 0;

#pragma unroll
    for (int cc = 1; cc < C; cc += 7) {       // chunks: 1-7, 8-14, 15-20
      f4 v[7];
#pragma unroll
      for (int j = 0; j < 7; ++j)
        if (cc + j < C) v[j] = pred[base + ((cc + j) << 16)];
#pragma unroll
      for (int j = 0; j < 7; ++j)
        if (cc + j < C) {
          const int c = cc + j;
          if (v[j][0] > best[0]) { best[0] = v[j][0]; i0 = c; }
          if (v[j][1] > best[1]) { best[1] = v[j][1]; i1 = c; }
          if (v[j][2] > best[2]) { best[2] = v[j][2]; i2 = c; }
          if (v[j][3] > best[3]) { best[3] = v[j][3]; i3 = c; }
        }
    }
    idx[q][0] = i0; idx[q][1] = i1; idx[q][2] = i2; idx[q][3] = i3;
    tg[q] = tgt[g];
  }

  // ---- per-wave ballot histogram: lane c accumulates class c ----
  unsigned long long m[GPT][4];
#pragma unroll
  for (int q = 0; q < GPT; ++q)
#pragma unroll
    for (int e = 0; e < 4; ++e)
      m[q][e] = __ballot(idx[q][e] == tg[q][e]);

  unsigned int cp = 0, ct = 0, ci = 0;
#pragma unroll
  for (int c = 0; c < C; ++c) {
    unsigned int np_ = 0, nt_ = 0, ni_ = 0;
#pragma unroll
    for (int q = 0; q < GPT; ++q)
#pragma unroll
      for (int e = 0; e < 4; ++e) {
        const unsigned long long pb = __ballot(idx[q][e] == c);
        np_ += (unsigned)__popcll(pb);
        ni_ += (unsigned)__popcll(pb & m[q][e]);
        nt_ += (unsigned)__popcll(__ballot(tg[q][e] == c));
      }
    if (lane == c) { cp = np_; ct = nt_; ci = ni_; }
  }

  // ---- wave -> block (LDS), block -> global ----
  if (lane < C) {
    atomicAdd(&sh[lane], cp);
    atomicAdd(&sh[C + lane], ct);
    atomicAdd(&sh[2 * C + lane], ci);
  }
  __syncthreads();
  if (tid < 3 * C) atomicAdd(&hist[tid], sh[tid]);

  // ---- last-block-done: fused finalize (saves a dispatch) ----
  __threadfence();                       // make this block's hist atomics visible
  __syncthreads();
  if (tid == 0) {
    const unsigned int o = atomicAdd(&hist[TICKET], 1u);
    sh_last = (o == NBLK - 1);
  }
  __syncthreads();
  if (sh_last && tid < 64) {
    float iou = 0.0f;
    if (tid < C) {
      // read through L2 coherence point (atomic RMW with 0) — no stale L1
      const float p = (float)atomicAdd(&hist[tid], 0u);
      const float t = (float)atomicAdd(&hist[C + tid], 0u);
      const float i = (float)atomicAdd(&hist[2 * C + tid], 0u);
      const float u = p + t - i;
      iou = (u > 0.0f) ? (i / (u + 1e-6f)) : 0.0f;
    }
#pragma unroll
    for (int off = 32; off > 0; off >>= 1) iou += __shfl_down(iou, off);
    if (tid == 0) out[0] = iou / (float)C;
  }
}

extern "C" void kernel_launch(void* const* d_in, const int* in_sizes, int n_in,
                              void* d_out, int out_size, void* d_ws, size_t ws_size,
                              hipStream_t stream) {
  const f4* pred = (const f4*)d_in[0];
  const i4* tgt  = (const i4*)d_in[1];
  float*    out  = (float*)d_out;
  unsigned int* hist = (unsigned int*)d_ws;

  // zero 63 counters + ticket every call (ws poisoned once, never re-poisoned)
  hipMemsetAsync(d_ws, 0, 64 * sizeof(unsigned int), stream);

  iou_kernel<<<NBLK, 256, 0, stream>>>(pred, tgt, hist, out);
}

// Round 5
// 107.318 us; speedup vs baseline: 3.5547x; 3.5547x over previous
//
#include <hip/hip_runtime.h>

#define C     21
#define HW4   65536      // float4 groups per 512x512 plane
#define NGRP  1048576    // 16*512*512/4
#define NBLK  4096       // NBLK*256 == NGRP: one pixel-group per thread

typedef float f4 __attribute__((ext_vector_type(4)));
typedef int   i4 __attribute__((ext_vector_type(4)));

__global__ __launch_bounds__(256) void iou_hist_kernel(
    const f4* __restrict__ pred, const i4* __restrict__ tgt,
    unsigned int* __restrict__ hist) {
  __shared__ unsigned int sh[3 * C];
  const int tid = threadIdx.x;
  if (tid < 3 * C) sh[tid] = 0;
  __syncthreads();

  const int lane = tid & 63;
  const int g    = blockIdx.x * 256 + tid;
  const int b    = g >> 16;                   // image index
  const int hw4  = g & (HW4 - 1);
  const int base = ((b * C) << 16) + hw4;     // f4 index of channel 0

  // ---- issue ALL loads first: tgt + 21 channels, no conditionals ----
  const i4 t = tgt[g];
  f4 v[C];
#pragma unroll
  for (int c = 0; c < C; ++c) v[c] = pred[base + (c << 16)];

  // ---- pure compare phase: argmax over 21 channels, 4 pixels ----
  f4 best = v[0];
  int i0 = 0, i1 = 0, i2 = 0, i3 = 0;
#pragma unroll
  for (int c = 1; c < C; ++c) {
    if (v[c][0] > best[0]) { best[0] = v[c][0]; i0 = c; }
    if (v[c][1] > best[1]) { best[1] = v[c][1]; i1 = c; }
    if (v[c][2] > best[2]) { best[2] = v[c][2]; i2 = c; }
    if (v[c][3] > best[3]) { best[3] = v[c][3]; i3 = c; }
  }

  // ---- per-wave ballot histogram: lane c owns class c ----
  const unsigned long long m0 = __ballot(i0 == t[0]);
  const unsigned long long m1 = __ballot(i1 == t[1]);
  const unsigned long long m2 = __ballot(i2 == t[2]);
  const unsigned long long m3 = __ballot(i3 == t[3]);

  unsigned int cp = 0, ct = 0, ci = 0;
#pragma unroll
  for (int c = 0; c < C; ++c) {
    const unsigned long long p0 = __ballot(i0 == c);
    const unsigned long long p1 = __ballot(i1 == c);
    const unsigned long long p2 = __ballot(i2 == c);
    const unsigned long long p3 = __ballot(i3 == c);
    const unsigned int np_ = (unsigned)__popcll(p0) + (unsigned)__popcll(p1)
                           + (unsigned)__popcll(p2) + (unsigned)__popcll(p3);
    const unsigned int ni_ = (unsigned)__popcll(p0 & m0) + (unsigned)__popcll(p1 & m1)
                           + (unsigned)__popcll(p2 & m2) + (unsigned)__popcll(p3 & m3);
    const unsigned int nt_ = (unsigned)__popcll(__ballot(t[0] == c))
                           + (unsigned)__popcll(__ballot(t[1] == c))
                           + (unsigned)__popcll(__ballot(t[2] == c))
                           + (unsigned)__popcll(__ballot(t[3] == c));
    if (lane == c) { cp = np_; ct = nt_; ci = ni_; }
  }

  // ---- wave -> block (LDS), block -> global ----
  if (lane < C) {
    atomicAdd(&sh[lane], cp);
    atomicAdd(&sh[C + lane], ct);
    atomicAdd(&sh[2 * C + lane], ci);
  }
  __syncthreads();
  if (tid < 3 * C) atomicAdd(&hist[tid], sh[tid]);
}

__global__ __launch_bounds__(64) void iou_finalize_kernel(
    const unsigned int* __restrict__ hist, float* __restrict__ out) {
  const int lane = threadIdx.x;
  float iou = 0.0f;
  if (lane < C) {
    const float p = (float)hist[lane];
    const float t = (float)hist[C + lane];
    const float i = (float)hist[2 * C + lane];
    const float u = p + t - i;
    iou = (u > 0.0f) ? (i / (u + 1e-6f)) : 0.0f;
  }
#pragma unroll
  for (int off = 32; off > 0; off >>= 1) iou += __shfl_down(iou, off);
  if (lane == 0) out[0] = iou / (float)C;
}

extern "C" void kernel_launch(void* const* d_in, const int* in_sizes, int n_in,
                              void* d_out, int out_size, void* d_ws, size_t ws_size,
                              hipStream_t stream) {
  const f4* pred = (const f4*)d_in[0];
  const i4* tgt  = (const i4*)d_in[1];
  float*    out  = (float*)d_out;
  unsigned int* hist = (unsigned int*)d_ws;

  // counters must start at zero every call (ws poisoned once, never re-poisoned)
  hipMemsetAsync(d_ws, 0, 3 * C * sizeof(unsigned int), stream);

  iou_hist_kernel<<<NBLK, 256, 0, stream>>>(pred, tgt, hist);
  iou_finalize_kernel<<<1, 64, 0, stream>>>(hist, out);
}